// Round 1
// 378.326 us; speedup vs baseline: 1.0445x; 1.0445x over previous
//
#include <hip/hip_runtime.h>
#include <math.h>

#define BH   32
#define LSEQ 4096
#define DK   128
#define DV   128
#define CH   32
#define NC   (LSEQ/CH)

typedef float4 f4;
typedef unsigned short u16;
typedef __attribute__((ext_vector_type(8))) short  bf16x8;   // MFMA A/B frag (8 bf16)
typedef __attribute__((ext_vector_type(4))) float  f32x4;    // MFMA C/D frag

#define MFMA16(a,b,c) __builtin_amdgcn_mfma_f32_16x16x32_bf16((a),(b),(c),0,0,0)

__device__ __forceinline__ float dot4(const f4 a, const f4 b) {
    return a.x*b.x + a.y*b.y + a.z*b.z + a.w*b.w;
}
__device__ __forceinline__ unsigned pk2(float a, float b) {   // 2x fp32 -> packed bf16 (RNE)
    unsigned ua = __builtin_bit_cast(unsigned, a);
    unsigned ub = __builtin_bit_cast(unsigned, b);
    ua = (ua + 0x7FFFu + ((ua >> 16) & 1u)) >> 16;
    ub = (ub + 0x7FFFu + ((ub >> 16) & 1u)) >> 16;
    return (ua & 0xFFFFu) | (ub << 16);
}
__device__ __forceinline__ u16 bf1(float a) {
    unsigned ua = __builtin_bit_cast(unsigned, a);
    ua = (ua + 0x7FFFu + ((ua >> 16) & 1u)) >> 16;
    return (u16)ua;
}

// ---------------------------------------------------------------------------
// Phase 1 (MFMA prep). Per (head,chunk):
//   qn=l2norm(q) -> qb16 ; kn=l2norm(k) -> kT16 (transposed)
//   A = tril_incl(qn kn^T) via MFMA -> A16 (bf16)
//   G = kn kn^T via MFMA ; T = fwd-subst inv of (I - strict_tril(diag(b) G))
//   T' = T diag(b) (bf16) ; u0 = T'@v -> v (fp32) ; w = -(T'@kn) -> wb16
// UNCHANGED from previous round (bit-exact baseline).
// ---------------------------------------------------------------------------
__global__ __launch_bounds__(256) void prep_kernel(
    const float* __restrict__ q, const float* __restrict__ k, float* __restrict__ v,
    const float* __restrict__ beta,
    u16* __restrict__ qb16, u16* __restrict__ wb16,
    u16* __restrict__ kT16, u16* __restrict__ A16)
{
    __shared__ u16 qn[CH][136];     // bf16 row-major (272B rows, 16B aligned)
    __shared__ u16 kn[CH][136];
    __shared__ u16 vT[DK][40];      // transposed v (no beta), 80B rows
    __shared__ u16 knT[DK][40];     // transposed kn
    __shared__ float Ts[CH][33];    // G -> T -> T'
    __shared__ float Af[CH][33];    // A fp32
    __shared__ u16 Tb[CH][40];      // bf16 T'
    __shared__ float redq[CH][8], redk[CH][8];
    __shared__ float bet[CH], scq[CH], sck[CH];

    const int tid = threadIdx.x;
    const int hh  = blockIdx.x >> 7;
    const int c   = blockIdx.x & (NC-1);
    const size_t rowbase = (size_t)hh * LSEQ + (size_t)c * CH;
    const size_t base    = rowbase * DK;
    const size_t tb      = (size_t)(hh * NC + c);

    const int r = tid >> 3, sub = tid & 7, d0 = sub * 16;
    const int wid = tid >> 6, lane = tid & 63, quad = lane >> 4, m16 = lane & 15;

    // ---- load q,k,v rows; row sum-of-squares ----
    f4 tq[4], tk[4], tv[4];
    float sq = 0.f, sk = 0.f;
#pragma unroll
    for (int m = 0; m < 4; ++m) {
        tq[m] = *(const f4*)(q + base + (size_t)r*DK + d0 + m*4);
        tk[m] = *(const f4*)(k + base + (size_t)r*DK + d0 + m*4);
        tv[m] = *(const f4*)(v + base + (size_t)r*DK + d0 + m*4);
        sq += dot4(tq[m], tq[m]);
        sk += dot4(tk[m], tk[m]);
    }
    redq[r][sub] = sq;
    redk[r][sub] = sk;
    if (tid < CH) bet[tid] = beta[rowbase + tid];
    __syncthreads();
    if (tid < CH) {
        float a = 0.f, b = 0.f;
#pragma unroll
        for (int j = 0; j < 8; ++j) { a += redq[tid][j]; b += redk[tid][j]; }
        scq[tid] = 1.0f / sqrtf(a + 1e-6f);
        sck[tid] = 1.0f / sqrtf(b + 1e-6f);
    }
    __syncthreads();
    const float aq = scq[r], ak = sck[r];
#pragma unroll
    for (int m = 0; m < 4; ++m) {
        tq[m].x *= aq; tq[m].y *= aq; tq[m].z *= aq; tq[m].w *= aq;
        tk[m].x *= ak; tk[m].y *= ak; tk[m].z *= ak; tk[m].w *= ak;
    }
    // qn,kn row-major bf16 LDS + qb16 global
    {
        uint4 p0, p1;
        p0.x = pk2(tq[0].x,tq[0].y); p0.y = pk2(tq[0].z,tq[0].w);
        p0.z = pk2(tq[1].x,tq[1].y); p0.w = pk2(tq[1].z,tq[1].w);
        p1.x = pk2(tq[2].x,tq[2].y); p1.y = pk2(tq[2].z,tq[2].w);
        p1.z = pk2(tq[3].x,tq[3].y); p1.w = pk2(tq[3].z,tq[3].w);
        *(uint4*)&qn[r][d0]     = p0;  *(uint4*)&qn[r][d0+8] = p1;
        *(uint4*)(qb16 + tb*4096 + (size_t)r*DK + d0)     = p0;
        *(uint4*)(qb16 + tb*4096 + (size_t)r*DK + d0 + 8) = p1;
        uint4 k0, k1;
        k0.x = pk2(tk[0].x,tk[0].y); k0.y = pk2(tk[0].z,tk[0].w);
        k0.z = pk2(tk[1].x,tk[1].y); k0.w = pk2(tk[1].z,tk[1].w);
        k1.x = pk2(tk[2].x,tk[2].y); k1.y = pk2(tk[2].z,tk[2].w);
        k1.z = pk2(tk[3].x,tk[3].y); k1.w = pk2(tk[3].z,tk[3].w);
        *(uint4*)&kn[r][d0]     = k0;  *(uint4*)&kn[r][d0+8] = k1;
    }
    // transposed bf16: knT[d][r], vT[d][r]
#pragma unroll
    for (int m = 0; m < 4; ++m) {
        knT[d0+m*4+0][r] = bf1(tk[m].x); knT[d0+m*4+1][r] = bf1(tk[m].y);
        knT[d0+m*4+2][r] = bf1(tk[m].z); knT[d0+m*4+3][r] = bf1(tk[m].w);
        vT [d0+m*4+0][r] = bf1(tv[m].x); vT [d0+m*4+1][r] = bf1(tv[m].y);
        vT [d0+m*4+2][r] = bf1(tv[m].z); vT [d0+m*4+3][r] = bf1(tv[m].w);
    }
    __syncthreads();

    // ---- kT16 global (coalesced) from knT ----
    {
        const int d = tid >> 1, jh = (tid & 1) * 16;
        uint4 z0 = *(const uint4*)&knT[d][jh];
        uint4 z1 = *(const uint4*)&knT[d][jh+8];
        *(uint4*)(kT16 + tb*4096 + (size_t)d*32 + jh)     = z0;
        *(uint4*)(kT16 + tb*4096 + (size_t)d*32 + jh + 8) = z1;
    }
    // ---- MFMA: A = qn kn^T , G = kn kn^T  (wave w -> tile (ti,tj)) ----
    {
        const int ti = wid >> 1, tj = wid & 1;
        f32x4 aA = {0.f,0.f,0.f,0.f}, aG = {0.f,0.f,0.f,0.f};
#pragma unroll
        for (int ks = 0; ks < 4; ++ks) {
            bf16x8 xq = *(const bf16x8*)&qn[ti*16+m16][ks*32 + quad*8];
            bf16x8 xk = *(const bf16x8*)&kn[ti*16+m16][ks*32 + quad*8];
            bf16x8 yk = *(const bf16x8*)&kn[tj*16+m16][ks*32 + quad*8];
            aA = MFMA16(xq, yk, aA);
            aG = MFMA16(xk, yk, aG);
        }
#pragma unroll
        for (int reg = 0; reg < 4; ++reg) {
            Af[ti*16 + quad*4 + reg][tj*16 + m16] = aA[reg];
            Ts[ti*16 + quad*4 + reg][tj*16 + m16] = aG[reg];
        }
    }
    __syncthreads();

    // ---- A16 write (masked) + T init = -strict_tril(diag(b) G) ----
    {
        const int i = r, j0 = sub * 4;
        float a[4];
#pragma unroll
        for (int jj = 0; jj < 4; ++jj)
            a[jj] = (j0+jj <= i) ? Af[i][j0+jj] : 0.f;
        uint2 pa; pa.x = pk2(a[0], a[1]); pa.y = pk2(a[2], a[3]);
        *(uint2*)(A16 + tb*1024 + (size_t)i*32 + j0) = pa;
        const float bi = bet[i];
#pragma unroll
        for (int jj = 0; jj < 4; ++jj) {
            const int j = j0 + jj;
            const float gv = Ts[i][j];
            Ts[i][j] = (j < i) ? -bi * gv : 0.f;
        }
    }
    __syncthreads();

    // ---- forward substitution: wave 0, registers + shuffles ----
    if (tid < 32) {
        float rr[32];
#pragma unroll
        for (int i = 0; i < 32; ++i) rr[i] = Ts[i][tid];
#pragma unroll
        for (int i = 1; i < 32; ++i) {
            float t = 0.f;
#pragma unroll
            for (int kk = 0; kk < i; ++kk)
                t += __shfl(rr[i], kk) * rr[kk];
            rr[i] += t;
        }
        const float bj = bet[tid];
#pragma unroll
        for (int i = 0; i < 32; ++i)
            Ts[i][tid] = ((i == tid) ? 1.0f : rr[i]) * bj;   // T' = T diag(b)
    }
    __syncthreads();
    // ---- pack T' -> bf16 ----
    {
        const int i = r, j0 = sub * 4;
        uint2 p; p.x = pk2(Ts[i][j0], Ts[i][j0+1]); p.y = pk2(Ts[i][j0+2], Ts[i][j0+3]);
        *(uint2*)&Tb[i][j0] = p;
    }
    __syncthreads();

    // ---- u0 = T'@v -> v ; w = -(T'@kn) -> wb16  (transposed orientation) ----
#pragma unroll
    for (int dt = 0; dt < 2; ++dt)
#pragma unroll
    for (int it = 0; it < 2; ++it) {
        const int drow = wid*32 + dt*16 + m16;
        bf16x8 av  = *(const bf16x8*)&vT[drow][quad*8];
        bf16x8 ak2 = *(const bf16x8*)&knT[drow][quad*8];
        bf16x8 bT  = *(const bf16x8*)&Tb[it*16 + m16][quad*8];
        f32x4 aU = {0.f,0.f,0.f,0.f}, aW = {0.f,0.f,0.f,0.f};
        aU = MFMA16(av,  bT, aU);
        aW = MFMA16(ak2, bT, aW);
        const int ii = it*16 + m16;               // chunk row
        const int dd = wid*32 + dt*16 + quad*4;   // feature col base
        f4 us; us.x = aU[0]; us.y = aU[1]; us.z = aU[2]; us.w = aU[3];
        *(f4*)(v + base + (size_t)ii*DK + dd) = us;
        uint2 pw; pw.x = pk2(-aW[0], -aW[1]); pw.y = pk2(-aW[2], -aW[3]);
        *(uint2*)(wb16 + tb*4096 + (size_t)ii*DK + dd) = pw;
    }
}

// ---------------------------------------------------------------------------
// Phase 2: single-barrier flip-flop scan. 1 block per (head, dv-group of 16);
// 4 waves. Per chunk:
//   - every wave computes full u = u0 + (-w)@S (8 MFMA, bit-identical across
//     waves), converts C-layout -> B-frag in-register (pk2 + 8 shfl)
//   - waves 0/1: S += kT@u over 64 dk rows each (4 reg-resident tiles),
//     write bf16 S^T to LDS for next chunk
//   - waves 2/3: o = q@S_old + A@u, store
//   - kT/q/A frags read direct from global into per-wave regs, prefetched
//     1 chunk ahead (no cross-wave reuse -> no LDS needed)
//   - w + u0 staged via LDS, register-prefetched 2 chunks ahead
//   - ONE __syncthreads per chunk (read [b], write [b^1])
// ---------------------------------------------------------------------------
__global__ __launch_bounds__(256, 1) void scan_kernel(
    const u16* __restrict__ qb16, const u16* __restrict__ wb16,
    const u16* __restrict__ kT16, const u16* __restrict__ A16,
    const float* __restrict__ u0, float* __restrict__ out)
{
    __shared__ u16   wbc[2][16][CH][8];   // -w, plane-major: [dk/8][chunk row][8]
    __shared__ u16   STc[2][16][16][8];   // S^T bf16: [dk/8][dv][8]
    __shared__ float uIT[2][16][36];      // u0^T fp32: [dv][chunk row] (+pad)

    const int tid  = threadIdx.x;
    const int hh   = blockIdx.x & (BH-1);
    const int g    = blockIdx.x >> 5;
    const int wid  = tid >> 6;
    const int lane = tid & 63;
    const int quad = lane >> 4;
    const int m16  = lane & 15;

    const int srow = tid >> 3;            // staging row 0..31
    const int spl  = (tid & 7) * 2;       // wb plane pair
    const int um   = (tid & 7) * 2;       // u0 dv col pair

    const u16* qg = qb16 + (size_t)hh * NC * 4096;
    const u16* wg = wb16 + (size_t)hh * NC * 4096;
    const u16* kg = kT16 + (size_t)hh * NC * 4096;
    const u16* Ag = A16  + (size_t)hh * NC * 1024;
    const float* ug = u0 + (size_t)hh * LSEQ * DK + g * 16;

    uint4 Ow0, Ow1, Ew0, Ew1; float2 Ou, Eu;
    bf16x8 F0 = {}, F1 = {}, F2 = {}, F3 = {}, AF = {};
    f32x4 S0 = {0.f,0.f,0.f,0.f}, S1 = {0.f,0.f,0.f,0.f};
    f32x4 S2 = {0.f,0.f,0.f,0.f}, S3 = {0.f,0.f,0.f,0.f};

#define PREF(P, cc) do { \
    const u16* wp_ = wg + (size_t)(cc)*4096 + (size_t)srow*DK + (tid&7)*16; \
    P##w0 = *(const uint4*)(wp_); \
    P##w1 = *(const uint4*)(wp_ + 8); \
    P##u  = *(const float2*)(ug + ((size_t)(cc)*CH + srow)*DK + um); \
} while (0)

#define STAGE(P, nb_) do { \
    *(uint4*)&wbc[nb_][spl  ][srow][0] = P##w0; \
    *(uint4*)&wbc[nb_][spl+1][srow][0] = P##w1; \
    uIT[nb_][um  ][srow] = P##u.x; \
    uIT[nb_][um+1][srow] = P##u.y; \
} while (0)

#define LOADFRAGS(cc) do { \
    if (wid < 2) { \
        const u16* kp_ = kg + (size_t)(cc)*4096 + (size_t)(wid*64 + m16)*32 + quad*8; \
        F0 = *(const bf16x8*)(kp_); \
        F1 = *(const bf16x8*)(kp_ + 16*32); \
        F2 = *(const bf16x8*)(kp_ + 32*32); \
        F3 = *(const bf16x8*)(kp_ + 48*32); \
    } else { \
        const u16* qp_ = qg + (size_t)(cc)*4096 + (size_t)((wid-2)*16 + m16)*DK + quad*8; \
        F0 = *(const bf16x8*)(qp_); \
        F1 = *(const bf16x8*)(qp_ + 32); \
        F2 = *(const bf16x8*)(qp_ + 64); \
        F3 = *(const bf16x8*)(qp_ + 96); \
        AF = *(const bf16x8*)(Ag + (size_t)(cc)*1024 + (size_t)((wid-2)*16 + m16)*32 + quad*8); \
    } \
} while (0)

    // ---- prologue: S^T[0] = 0; stage chunk 0; prefetch chunks 1,2; frags 0 ----
    for (int i = tid; i < 16*16*8; i += 256) (&STc[0][0][0][0])[i] = 0;
    PREF(O, 0);
    STAGE(O, 0);
    PREF(O, 1);
    PREF(E, 2);
    LOADFRAGS(0);
    __syncthreads();

#define BODY(c, b, P) do { \
    const int nb = (b) ^ 1; \
    STAGE(P, nb); \
    { const int c3_ = ((c)+3 < NC) ? (c)+3 : NC-1; PREF(P, c3_); } \
    /* ---- u = u0 + (-w)@S_old : both 16-row tiles, all waves ---- */ \
    f32x4 u0a = *(const f32x4*)&uIT[b][m16][quad*4]; \
    f32x4 u1a = *(const f32x4*)&uIT[b][m16][16 + quad*4]; \
    f32x4 u0b = {0.f,0.f,0.f,0.f}, u1b = {0.f,0.f,0.f,0.f}; \
    bf16x8 sf0 = *(const bf16x8*)&STc[b][quad    ][m16][0]; \
    bf16x8 sf1 = *(const bf16x8*)&STc[b][ 4+quad ][m16][0]; \
    bf16x8 sf2 = *(const bf16x8*)&STc[b][ 8+quad ][m16][0]; \
    bf16x8 sf3 = *(const bf16x8*)&STc[b][12+quad ][m16][0]; \
    u0a = MFMA16(*(const bf16x8*)&wbc[b][quad    ][   m16][0], sf0, u0a); \
    u1a = MFMA16(*(const bf16x8*)&wbc[b][quad    ][16+m16][0], sf0, u1a); \
    u0b = MFMA16(*(const bf16x8*)&wbc[b][ 4+quad ][   m16][0], sf1, u0b); \
    u1b = MFMA16(*(const bf16x8*)&wbc[b][ 4+quad ][16+m16][0], sf1, u1b); \
    u0a = MFMA16(*(const bf16x8*)&wbc[b][ 8+quad ][   m16][0], sf2, u0a); \
    u1a = MFMA16(*(const bf16x8*)&wbc[b][ 8+quad ][16+m16][0], sf2, u1a); \
    u0b = MFMA16(*(const bf16x8*)&wbc[b][12+quad ][   m16][0], sf3, u0b); \
    u1b = MFMA16(*(const bf16x8*)&wbc[b][12+quad ][16+m16][0], sf3, u1b); \
    u0a[0]+=u0b[0]; u0a[1]+=u0b[1]; u0a[2]+=u0b[2]; u0a[3]+=u0b[3]; \
    u1a[0]+=u1b[0]; u1a[1]+=u1b[1]; u1a[2]+=u1b[2]; u1a[3]+=u1b[3]; \
    /* ---- pack + in-register C->B transpose ---- */ \
    const unsigned W00 = pk2(u0a[0], u0a[1]), W01 = pk2(u0a[2], u0a[3]); \
    const unsigned W10 = pk2(u1a[0], u1a[1]), W11 = pk2(u1a[2], u1a[3]); \
    const int s0l_ = (2*(quad&1))*16 + m16, s1l_ = s0l_ + 16; \
    union { unsigned w[4]; bf16x8 v; } uc_; \
    { const unsigned a0_ = __shfl((int)W00, s0l_), b0_ = __shfl((int)W10, s0l_); \
      const unsigned a1_ = __shfl((int)W01, s0l_), b1_ = __shfl((int)W11, s0l_); \
      const unsigned a2_ = __shfl((int)W00, s1l_), b2_ = __shfl((int)W10, s1l_); \
      const unsigned a3_ = __shfl((int)W01, s1l_), b3_ = __shfl((int)W11, s1l_); \
      const bool hi_ = (quad >= 2); \
      uc_.w[0] = hi_ ? b0_ : a0_; uc_.w[1] = hi_ ? b1_ : a1_; \
      uc_.w[2] = hi_ ? b2_ : a2_; uc_.w[3] = hi_ ? b3_ : a3_; } \
    const bf16x8 ub_ = uc_.v; \
    if (wid < 2) { \
        /* ---- S += kT@u over dk rows [wid*64, wid*64+64) ---- */ \
        const int db_ = wid * 64; \
        S0 = MFMA16(F0, ub_, S0); \
        S1 = MFMA16(F1, ub_, S1); \
        S2 = MFMA16(F2, ub_, S2); \
        S3 = MFMA16(F3, ub_, S3); \
        uint2 p_; \
        p_.x = pk2(S0[0],S0[1]); p_.y = pk2(S0[2],S0[3]); \
        *(uint2*)&STc[nb][(db_>>3)   + (quad>>1)][m16][4*(quad&1)] = p_; \
        p_.x = pk2(S1[0],S1[1]); p_.y = pk2(S1[2],S1[3]); \
        *(uint2*)&STc[nb][(db_>>3)+2 + (quad>>1)][m16][4*(quad&1)] = p_; \
        p_.x = pk2(S2[0],S2[1]); p_.y = pk2(S2[2],S2[3]); \
        *(uint2*)&STc[nb][(db_>>3)+4 + (quad>>1)][m16][4*(quad&1)] = p_; \
        p_.x = pk2(S3[0],S3[1]); p_.y = pk2(S3[2],S3[3]); \
        *(uint2*)&STc[nb][(db_>>3)+6 + (quad>>1)][m16][4*(quad&1)] = p_; \
    } else { \
        /* ---- o = q@S_old + A@u ---- */ \
        f32x4 Za = {0.f,0.f,0.f,0.f}, Zb = {0.f,0.f,0.f,0.f}; \
        Za = MFMA16(F0, sf0, Za); \
        Zb = MFMA16(F1, sf1, Zb); \
        Za = MFMA16(F2, sf2, Za); \
        Zb = MFMA16(F3, sf3, Zb); \
        Za[0]+=Zb[0]; Za[1]+=Zb[1]; Za[2]+=Zb[2]; Za[3]+=Zb[3]; \
        Za = MFMA16(AF, ub_, Za); \
        float* op_ = out + ((size_t)hh*LSEQ + (size_t)(c)*CH + (wid-2)*16 + quad*4)*DV \
                         + g*16 + m16; \
        op_[0] = Za[0]; op_[DV] = Za[1]; op_[2*DV] = Za[2]; op_[3*DV] = Za[3]; \
    } \
    { const int c1_ = ((c)+1 < NC) ? (c)+1 : NC-1; LOADFRAGS(c1_); } \
    __syncthreads(); \
} while (0)

    for (int c = 0; c < NC; c += 2) {
        BODY(c,     0, O);
        BODY(c + 1, 1, E);
    }

    // ---- final state -> out tail (b,h,dk,dv) fp32 ----
    if (wid < 2) {
        float* sp = out + (size_t)BH*LSEQ*DV
                        + ((size_t)hh*DK + wid*64 + quad*4)*DV + g*16 + m16;
        sp[0] = S0[0]; sp[DV] = S0[1]; sp[2*DV] = S0[2]; sp[3*DV] = S0[3];
        sp += (size_t)16*DV;
        sp[0] = S1[0]; sp[DV] = S1[1]; sp[2*DV] = S1[2]; sp[3*DV] = S1[3];
        sp += (size_t)16*DV;
        sp[0] = S2[0]; sp[DV] = S2[1]; sp[2*DV] = S2[2]; sp[3*DV] = S2[3];
        sp += (size_t)16*DV;
        sp[0] = S3[0]; sp[DV] = S3[1]; sp[2*DV] = S3[2]; sp[3*DV] = S3[3];
    }
#undef BODY
#undef LOADFRAGS
#undef STAGE
#undef PREF
}

extern "C" void kernel_launch(void* const* d_in, const int* in_sizes, int n_in,
                              void* d_out, int out_size, void* d_ws, size_t ws_size,
                              hipStream_t stream) {
    (void)in_sizes; (void)n_in; (void)out_size; (void)ws_size;
    const float* q = (const float*)d_in[0];
    const float* k = (const float*)d_in[1];
    float* v = (float*)d_in[2];
    const float* beta = (const float*)d_in[3];
    float* out = (float*)d_out;

    const size_t NE = (size_t)BH * LSEQ * DK;
    u16* qb16 = (u16*)d_ws;
    u16* wb16 = qb16 + NE;
    u16* kT16 = wb16 + NE;
    u16* A16  = kT16 + NE;

    prep_kernel<<<dim3(BH*NC), dim3(256), 0, stream>>>(q, k, v, beta, qb16, wb16, kT16, A16);
    scan_kernel<<<dim3(8*BH), dim3(256), 0, stream>>>(qb16, wb16, kT16, A16, v, out);
}

// Round 2
// 355.731 us; speedup vs baseline: 1.1109x; 1.0635x over previous
//
#include <hip/hip_runtime.h>
#include <math.h>

#define BH   32
#define LSEQ 4096
#define DK   128
#define DV   128
#define CH   32
#define NC   (LSEQ/CH)

typedef float4 f4;
typedef unsigned short u16;
typedef __attribute__((ext_vector_type(8))) short  bf16x8;   // MFMA A/B frag (8 bf16)
typedef __attribute__((ext_vector_type(4))) float  f32x4;    // MFMA C/D frag

#define MFMA16(a,b,c) __builtin_amdgcn_mfma_f32_16x16x32_bf16((a),(b),(c),0,0,0)

__device__ __forceinline__ float dot4(const f4 a, const f4 b) {
    return a.x*b.x + a.y*b.y + a.z*b.z + a.w*b.w;
}
__device__ __forceinline__ unsigned pk2(float a, float b) {   // 2x fp32 -> packed bf16 (RNE)
    unsigned ua = __builtin_bit_cast(unsigned, a);
    unsigned ub = __builtin_bit_cast(unsigned, b);
    ua = (ua + 0x7FFFu + ((ua >> 16) & 1u)) >> 16;
    ub = (ub + 0x7FFFu + ((ub >> 16) & 1u)) >> 16;
    return (ua & 0xFFFFu) | (ub << 16);
}
__device__ __forceinline__ u16 bf1(float a) {
    unsigned ua = __builtin_bit_cast(unsigned, a);
    ua = (ua + 0x7FFFu + ((ua >> 16) & 1u)) >> 16;
    return (u16)ua;
}

// ---------------------------------------------------------------------------
// Phase 1 (MFMA prep). Per (head,chunk):
//   qn=l2norm(q) -> qb16 ; kn=l2norm(k) -> kT16 (transposed)
//   A = tril_incl(qn kn^T) via MFMA -> A16 (bf16)
//   G = kn kn^T via MFMA ; T = fwd-subst inv of (I - strict_tril(diag(b) G))
//   T' = T diag(b) (bf16) ; u0 = T'@v -> v (fp32) ; w = -(T'@kn) -> wb16
// CHANGE vs prev round: wb16 written in scan-staging-linear order
//   (flat u16 idx = (dk>>3)*256 + row*8 + (dk&7)) so scan's PREF is a
//   coalesced 32B/thread read and STAGE is a stride-1 conflict-free LDS write.
// ---------------------------------------------------------------------------
__global__ __launch_bounds__(256) void prep_kernel(
    const float* __restrict__ q, const float* __restrict__ k, float* __restrict__ v,
    const float* __restrict__ beta,
    u16* __restrict__ qb16, u16* __restrict__ wb16,
    u16* __restrict__ kT16, u16* __restrict__ A16)
{
    __shared__ u16 qn[CH][136];     // bf16 row-major (272B rows, 16B aligned)
    __shared__ u16 kn[CH][136];
    __shared__ u16 vT[DK][40];      // transposed v (no beta), 80B rows
    __shared__ u16 knT[DK][40];     // transposed kn
    __shared__ float Ts[CH][33];    // G -> T -> T'
    __shared__ float Af[CH][33];    // A fp32
    __shared__ u16 Tb[CH][40];      // bf16 T'
    __shared__ float redq[CH][8], redk[CH][8];
    __shared__ float bet[CH], scq[CH], sck[CH];

    const int tid = threadIdx.x;
    const int hh  = blockIdx.x >> 7;
    const int c   = blockIdx.x & (NC-1);
    const size_t rowbase = (size_t)hh * LSEQ + (size_t)c * CH;
    const size_t base    = rowbase * DK;
    const size_t tb      = (size_t)(hh * NC + c);

    const int r = tid >> 3, sub = tid & 7, d0 = sub * 16;
    const int wid = tid >> 6, lane = tid & 63, quad = lane >> 4, m16 = lane & 15;

    // ---- load q,k,v rows; row sum-of-squares ----
    f4 tq[4], tk[4], tv[4];
    float sq = 0.f, sk = 0.f;
#pragma unroll
    for (int m = 0; m < 4; ++m) {
        tq[m] = *(const f4*)(q + base + (size_t)r*DK + d0 + m*4);
        tk[m] = *(const f4*)(k + base + (size_t)r*DK + d0 + m*4);
        tv[m] = *(const f4*)(v + base + (size_t)r*DK + d0 + m*4);
        sq += dot4(tq[m], tq[m]);
        sk += dot4(tk[m], tk[m]);
    }
    redq[r][sub] = sq;
    redk[r][sub] = sk;
    if (tid < CH) bet[tid] = beta[rowbase + tid];
    __syncthreads();
    if (tid < CH) {
        float a = 0.f, b = 0.f;
#pragma unroll
        for (int j = 0; j < 8; ++j) { a += redq[tid][j]; b += redk[tid][j]; }
        scq[tid] = 1.0f / sqrtf(a + 1e-6f);
        sck[tid] = 1.0f / sqrtf(b + 1e-6f);
    }
    __syncthreads();
    const float aq = scq[r], ak = sck[r];
#pragma unroll
    for (int m = 0; m < 4; ++m) {
        tq[m].x *= aq; tq[m].y *= aq; tq[m].z *= aq; tq[m].w *= aq;
        tk[m].x *= ak; tk[m].y *= ak; tk[m].z *= ak; tk[m].w *= ak;
    }
    // qn,kn row-major bf16 LDS + qb16 global
    {
        uint4 p0, p1;
        p0.x = pk2(tq[0].x,tq[0].y); p0.y = pk2(tq[0].z,tq[0].w);
        p0.z = pk2(tq[1].x,tq[1].y); p0.w = pk2(tq[1].z,tq[1].w);
        p1.x = pk2(tq[2].x,tq[2].y); p1.y = pk2(tq[2].z,tq[2].w);
        p1.z = pk2(tq[3].x,tq[3].y); p1.w = pk2(tq[3].z,tq[3].w);
        *(uint4*)&qn[r][d0]     = p0;  *(uint4*)&qn[r][d0+8] = p1;
        *(uint4*)(qb16 + tb*4096 + (size_t)r*DK + d0)     = p0;
        *(uint4*)(qb16 + tb*4096 + (size_t)r*DK + d0 + 8) = p1;
        uint4 k0, k1;
        k0.x = pk2(tk[0].x,tk[0].y); k0.y = pk2(tk[0].z,tk[0].w);
        k0.z = pk2(tk[1].x,tk[1].y); k0.w = pk2(tk[1].z,tk[1].w);
        k1.x = pk2(tk[2].x,tk[2].y); k1.y = pk2(tk[2].z,tk[2].w);
        k1.z = pk2(tk[3].x,tk[3].y); k1.w = pk2(tk[3].z,tk[3].w);
        *(uint4*)&kn[r][d0]     = k0;  *(uint4*)&kn[r][d0+8] = k1;
    }
    // transposed bf16: knT[d][r], vT[d][r]
#pragma unroll
    for (int m = 0; m < 4; ++m) {
        knT[d0+m*4+0][r] = bf1(tk[m].x); knT[d0+m*4+1][r] = bf1(tk[m].y);
        knT[d0+m*4+2][r] = bf1(tk[m].z); knT[d0+m*4+3][r] = bf1(tk[m].w);
        vT [d0+m*4+0][r] = bf1(tv[m].x); vT [d0+m*4+1][r] = bf1(tv[m].y);
        vT [d0+m*4+2][r] = bf1(tv[m].z); vT [d0+m*4+3][r] = bf1(tv[m].w);
    }
    __syncthreads();

    // ---- kT16 global (coalesced) from knT ----
    {
        const int d = tid >> 1, jh = (tid & 1) * 16;
        uint4 z0 = *(const uint4*)&knT[d][jh];
        uint4 z1 = *(const uint4*)&knT[d][jh+8];
        *(uint4*)(kT16 + tb*4096 + (size_t)d*32 + jh)     = z0;
        *(uint4*)(kT16 + tb*4096 + (size_t)d*32 + jh + 8) = z1;
    }
    // ---- MFMA: A = qn kn^T , G = kn kn^T  (wave w -> tile (ti,tj)) ----
    {
        const int ti = wid >> 1, tj = wid & 1;
        f32x4 aA = {0.f,0.f,0.f,0.f}, aG = {0.f,0.f,0.f,0.f};
#pragma unroll
        for (int ks = 0; ks < 4; ++ks) {
            bf16x8 xq = *(const bf16x8*)&qn[ti*16+m16][ks*32 + quad*8];
            bf16x8 xk = *(const bf16x8*)&kn[ti*16+m16][ks*32 + quad*8];
            bf16x8 yk = *(const bf16x8*)&kn[tj*16+m16][ks*32 + quad*8];
            aA = MFMA16(xq, yk, aA);
            aG = MFMA16(xk, yk, aG);
        }
#pragma unroll
        for (int reg = 0; reg < 4; ++reg) {
            Af[ti*16 + quad*4 + reg][tj*16 + m16] = aA[reg];
            Ts[ti*16 + quad*4 + reg][tj*16 + m16] = aG[reg];
        }
    }
    __syncthreads();

    // ---- A16 write (masked) + T init = -strict_tril(diag(b) G) ----
    {
        const int i = r, j0 = sub * 4;
        float a[4];
#pragma unroll
        for (int jj = 0; jj < 4; ++jj)
            a[jj] = (j0+jj <= i) ? Af[i][j0+jj] : 0.f;
        uint2 pa; pa.x = pk2(a[0], a[1]); pa.y = pk2(a[2], a[3]);
        *(uint2*)(A16 + tb*1024 + (size_t)i*32 + j0) = pa;
        const float bi = bet[i];
#pragma unroll
        for (int jj = 0; jj < 4; ++jj) {
            const int j = j0 + jj;
            const float gv = Ts[i][j];
            Ts[i][j] = (j < i) ? -bi * gv : 0.f;
        }
    }
    __syncthreads();

    // ---- forward substitution: wave 0, registers + shuffles ----
    if (tid < 32) {
        float rr[32];
#pragma unroll
        for (int i = 0; i < 32; ++i) rr[i] = Ts[i][tid];
#pragma unroll
        for (int i = 1; i < 32; ++i) {
            float t = 0.f;
#pragma unroll
            for (int kk = 0; kk < i; ++kk)
                t += __shfl(rr[i], kk) * rr[kk];
            rr[i] += t;
        }
        const float bj = bet[tid];
#pragma unroll
        for (int i = 0; i < 32; ++i)
            Ts[i][tid] = ((i == tid) ? 1.0f : rr[i]) * bj;   // T' = T diag(b)
    }
    __syncthreads();
    // ---- pack T' -> bf16 ----
    {
        const int i = r, j0 = sub * 4;
        uint2 p; p.x = pk2(Ts[i][j0], Ts[i][j0+1]); p.y = pk2(Ts[i][j0+2], Ts[i][j0+3]);
        *(uint2*)&Tb[i][j0] = p;
    }
    __syncthreads();

    // ---- u0 = T'@v -> v ; w = -(T'@kn) -> wb16  (transposed orientation) ----
#pragma unroll
    for (int dt = 0; dt < 2; ++dt)
#pragma unroll
    for (int it = 0; it < 2; ++it) {
        const int drow = wid*32 + dt*16 + m16;
        bf16x8 av  = *(const bf16x8*)&vT[drow][quad*8];
        bf16x8 ak2 = *(const bf16x8*)&knT[drow][quad*8];
        bf16x8 bT  = *(const bf16x8*)&Tb[it*16 + m16][quad*8];
        f32x4 aU = {0.f,0.f,0.f,0.f}, aW = {0.f,0.f,0.f,0.f};
        aU = MFMA16(av,  bT, aU);
        aW = MFMA16(ak2, bT, aW);
        const int ii = it*16 + m16;               // chunk row
        const int dd = wid*32 + dt*16 + quad*4;   // feature col base
        f4 us; us.x = aU[0]; us.y = aU[1]; us.z = aU[2]; us.w = aU[3];
        *(f4*)(v + base + (size_t)ii*DK + dd) = us;
        uint2 pw; pw.x = pk2(-aW[0], -aW[1]); pw.y = pk2(-aW[2], -aW[3]);
        // staging-linear layout: plane = dd>>3 (8 dk per plane), row = ii
        *(uint2*)(wb16 + tb*4096 + (size_t)((dd>>3)*256 + ii*8 + (dd&7))) = pw;
    }
}

// ---------------------------------------------------------------------------
// Phase 2: single-raw-barrier flip-flop scan. 1 block per (head, dv-group);
// 4 waves. Changes vs prev round:
//   - loop barrier = lgkmcnt(0) + raw s_barrier (NO vmcnt drain -> global
//     prefetches stay in flight across chunks)
//   - F/AF frags double-buffered (2-chunk-deep register prefetch)
//   - w staging: coalesced 32B/thread global read, stride-1 LDS write
// ---------------------------------------------------------------------------
__global__ __launch_bounds__(256, 1) void scan_kernel(
    const u16* __restrict__ qb16, const u16* __restrict__ wb16,
    const u16* __restrict__ kT16, const u16* __restrict__ A16,
    const float* __restrict__ u0, float* __restrict__ out)
{
    __shared__ __align__(16) u16   wbc[2][16][CH][8];   // -w, plane-major: [dk/8][row][8]
    __shared__ __align__(16) u16   STc[2][16][16][8];   // S^T bf16: [dk/8][dv][8]
    __shared__ float uIT[2][16][36];                    // u0^T fp32: [dv][row] (+pad)

    const int tid  = threadIdx.x;
    const int hh   = blockIdx.x & (BH-1);
    const int g    = blockIdx.x >> 5;
    const int wid  = tid >> 6;
    const int lane = tid & 63;
    const int quad = lane >> 4;
    const int m16  = lane & 15;

    const int srow = tid >> 3;            // u0 staging row 0..31
    const int um   = (tid & 7) * 2;       // u0 dv col pair

    const u16* qg = qb16 + (size_t)hh * NC * 4096;
    const u16* wg = wb16 + (size_t)hh * NC * 4096;
    const u16* kg = kT16 + (size_t)hh * NC * 4096;
    const u16* Ag = A16  + (size_t)hh * NC * 1024;
    const float* ug = u0 + (size_t)hh * LSEQ * DK + g * 16;

    uint4 Ow0, Ow1, Ew0, Ew1; float2 Ou, Eu;
    bf16x8 OF0 = {}, OF1 = {}, OF2 = {}, OF3 = {}, OAF = {};
    bf16x8 EF0 = {}, EF1 = {}, EF2 = {}, EF3 = {}, EAF = {};
    f32x4 S0 = {0.f,0.f,0.f,0.f}, S1 = {0.f,0.f,0.f,0.f};
    f32x4 S2 = {0.f,0.f,0.f,0.f}, S3 = {0.f,0.f,0.f,0.f};

#define PREF(P, cc) do { \
    const u16* wp_ = wg + (size_t)(cc)*4096 + (size_t)tid*16; \
    P##w0 = *(const uint4*)(wp_); \
    P##w1 = *(const uint4*)(wp_ + 8); \
    P##u  = *(const float2*)(ug + ((size_t)(cc)*CH + srow)*DK + um); \
} while (0)

#define STAGE(P, nb_) do { \
    u16* wl_ = ((u16*)wbc) + (size_t)(nb_)*4096 + (size_t)tid*16; \
    *(uint4*)(wl_)     = P##w0; \
    *(uint4*)(wl_ + 8) = P##w1; \
    uIT[nb_][um  ][srow] = P##u.x; \
    uIT[nb_][um+1][srow] = P##u.y; \
} while (0)

#define LOADFRAGS(P, cc) do { \
    if (wid < 2) { \
        const u16* kp_ = kg + (size_t)(cc)*4096 + (size_t)(wid*64 + m16)*32 + quad*8; \
        P##F0 = *(const bf16x8*)(kp_); \
        P##F1 = *(const bf16x8*)(kp_ + 16*32); \
        P##F2 = *(const bf16x8*)(kp_ + 32*32); \
        P##F3 = *(const bf16x8*)(kp_ + 48*32); \
    } else { \
        const u16* qp_ = qg + (size_t)(cc)*4096 + (size_t)((wid-2)*16 + m16)*DK + quad*8; \
        P##F0 = *(const bf16x8*)(qp_); \
        P##F1 = *(const bf16x8*)(qp_ + 32); \
        P##F2 = *(const bf16x8*)(qp_ + 64); \
        P##F3 = *(const bf16x8*)(qp_ + 96); \
        P##AF = *(const bf16x8*)(Ag + (size_t)(cc)*1024 + (size_t)((wid-2)*16 + m16)*32 + quad*8); \
    } \
} while (0)

#define RAWBAR() do { \
    asm volatile("s_waitcnt lgkmcnt(0)" ::: "memory"); \
    __builtin_amdgcn_s_barrier(); \
    __builtin_amdgcn_sched_barrier(0); \
} while (0)

    // ---- prologue: S^T[0]=0; stage chunk 0; prefetch chunks 1,2; frags 0,1 ----
    for (int i = tid; i < 16*16*8; i += 256) (&STc[0][0][0][0])[i] = 0;
    PREF(O, 0);
    STAGE(O, 0);
    PREF(O, 1);
    PREF(E, 2);
    LOADFRAGS(O, 0);
    LOADFRAGS(E, 1);
    RAWBAR();

#define BODY(c, b, P) do { \
    const int nb = (b) ^ 1; \
    STAGE(P, nb); \
    { const int c3_ = ((c)+3 < NC) ? (c)+3 : NC-1; PREF(P, c3_); } \
    /* ---- u = u0 + (-w)@S_old : both 16-row tiles, all waves ---- */ \
    f32x4 u0a = *(const f32x4*)&uIT[b][m16][quad*4]; \
    f32x4 u1a = *(const f32x4*)&uIT[b][m16][16 + quad*4]; \
    f32x4 u0b = {0.f,0.f,0.f,0.f}, u1b = {0.f,0.f,0.f,0.f}; \
    bf16x8 sf0 = *(const bf16x8*)&STc[b][quad    ][m16][0]; \
    bf16x8 sf1 = *(const bf16x8*)&STc[b][ 4+quad ][m16][0]; \
    bf16x8 sf2 = *(const bf16x8*)&STc[b][ 8+quad ][m16][0]; \
    bf16x8 sf3 = *(const bf16x8*)&STc[b][12+quad ][m16][0]; \
    u0a = MFMA16(*(const bf16x8*)&wbc[b][quad    ][   m16][0], sf0, u0a); \
    u1a = MFMA16(*(const bf16x8*)&wbc[b][quad    ][16+m16][0], sf0, u1a); \
    u0b = MFMA16(*(const bf16x8*)&wbc[b][ 4+quad ][   m16][0], sf1, u0b); \
    u1b = MFMA16(*(const bf16x8*)&wbc[b][ 4+quad ][16+m16][0], sf1, u1b); \
    u0a = MFMA16(*(const bf16x8*)&wbc[b][ 8+quad ][   m16][0], sf2, u0a); \
    u1a = MFMA16(*(const bf16x8*)&wbc[b][ 8+quad ][16+m16][0], sf2, u1a); \
    u0b = MFMA16(*(const bf16x8*)&wbc[b][12+quad ][   m16][0], sf3, u0b); \
    u1b = MFMA16(*(const bf16x8*)&wbc[b][12+quad ][16+m16][0], sf3, u1b); \
    u0a[0]+=u0b[0]; u0a[1]+=u0b[1]; u0a[2]+=u0b[2]; u0a[3]+=u0b[3]; \
    u1a[0]+=u1b[0]; u1a[1]+=u1b[1]; u1a[2]+=u1b[2]; u1a[3]+=u1b[3]; \
    /* ---- pack + in-register C->B transpose ---- */ \
    const unsigned W00 = pk2(u0a[0], u0a[1]), W01 = pk2(u0a[2], u0a[3]); \
    const unsigned W10 = pk2(u1a[0], u1a[1]), W11 = pk2(u1a[2], u1a[3]); \
    const int s0l_ = (2*(quad&1))*16 + m16, s1l_ = s0l_ + 16; \
    union { unsigned w[4]; bf16x8 v; } uc_; \
    { const unsigned a0_ = __shfl((int)W00, s0l_), b0_ = __shfl((int)W10, s0l_); \
      const unsigned a1_ = __shfl((int)W01, s0l_), b1_ = __shfl((int)W11, s0l_); \
      const unsigned a2_ = __shfl((int)W00, s1l_), b2_ = __shfl((int)W10, s1l_); \
      const unsigned a3_ = __shfl((int)W01, s1l_), b3_ = __shfl((int)W11, s1l_); \
      const bool hi_ = (quad >= 2); \
      uc_.w[0] = hi_ ? b0_ : a0_; uc_.w[1] = hi_ ? b1_ : a1_; \
      uc_.w[2] = hi_ ? b2_ : a2_; uc_.w[3] = hi_ ? b3_ : a3_; } \
    const bf16x8 ub_ = uc_.v; \
    if (wid < 2) { \
        /* ---- S += kT@u over dk rows [wid*64, wid*64+64) ---- */ \
        const int db_ = wid * 64; \
        S0 = MFMA16(P##F0, ub_, S0); \
        S1 = MFMA16(P##F1, ub_, S1); \
        S2 = MFMA16(P##F2, ub_, S2); \
        S3 = MFMA16(P##F3, ub_, S3); \
        uint2 p_; \
        p_.x = pk2(S0[0],S0[1]); p_.y = pk2(S0[2],S0[3]); \
        *(uint2*)&STc[nb][(db_>>3)   + (quad>>1)][m16][4*(quad&1)] = p_; \
        p_.x = pk2(S1[0],S1[1]); p_.y = pk2(S1[2],S1[3]); \
        *(uint2*)&STc[nb][(db_>>3)+2 + (quad>>1)][m16][4*(quad&1)] = p_; \
        p_.x = pk2(S2[0],S2[1]); p_.y = pk2(S2[2],S2[3]); \
        *(uint2*)&STc[nb][(db_>>3)+4 + (quad>>1)][m16][4*(quad&1)] = p_; \
        p_.x = pk2(S3[0],S3[1]); p_.y = pk2(S3[2],S3[3]); \
        *(uint2*)&STc[nb][(db_>>3)+6 + (quad>>1)][m16][4*(quad&1)] = p_; \
    } else { \
        /* ---- o = q@S_old + A@u ---- */ \
        f32x4 Za = {0.f,0.f,0.f,0.f}, Zb = {0.f,0.f,0.f,0.f}; \
        Za = MFMA16(P##F0, sf0, Za); \
        Zb = MFMA16(P##F1, sf1, Zb); \
        Za = MFMA16(P##F2, sf2, Za); \
        Zb = MFMA16(P##F3, sf3, Zb); \
        Za[0]+=Zb[0]; Za[1]+=Zb[1]; Za[2]+=Zb[2]; Za[3]+=Zb[3]; \
        Za = MFMA16(P##AF, ub_, Za); \
        float* op_ = out + ((size_t)hh*LSEQ + (size_t)(c)*CH + (wid-2)*16 + quad*4)*DV \
                         + g*16 + m16; \
        op_[0] = Za[0]; op_[DV] = Za[1]; op_[2*DV] = Za[2]; op_[3*DV] = Za[3]; \
    } \
    /* refill this parity's frag set for chunk c+2 (2-deep pipeline) */ \
    { const int c2_ = ((c)+2 < NC) ? (c)+2 : NC-1; LOADFRAGS(P, c2_); } \
    RAWBAR(); \
} while (0)

    for (int c = 0; c < NC; c += 2) {
        BODY(c,     0, O);
        BODY(c + 1, 1, E);
    }

    // ---- final state -> out tail (b,h,dk,dv) fp32 ----
    if (wid < 2) {
        float* sp = out + (size_t)BH*LSEQ*DV
                        + ((size_t)hh*DK + wid*64 + quad*4)*DV + g*16 + m16;
        sp[0] = S0[0]; sp[DV] = S0[1]; sp[2*DV] = S0[2]; sp[3*DV] = S0[3];
        sp += (size_t)16*DV;
        sp[0] = S1[0]; sp[DV] = S1[1]; sp[2*DV] = S1[2]; sp[3*DV] = S1[3];
        sp += (size_t)16*DV;
        sp[0] = S2[0]; sp[DV] = S2[1]; sp[2*DV] = S2[2]; sp[3*DV] = S2[3];
        sp += (size_t)16*DV;
        sp[0] = S3[0]; sp[DV] = S3[1]; sp[2*DV] = S3[2]; sp[3*DV] = S3[3];
    }
#undef BODY
#undef RAWBAR
#undef LOADFRAGS
#undef STAGE
#undef PREF
}

extern "C" void kernel_launch(void* const* d_in, const int* in_sizes, int n_in,
                              void* d_out, int out_size, void* d_ws, size_t ws_size,
                              hipStream_t stream) {
    (void)in_sizes; (void)n_in; (void)out_size; (void)ws_size;
    const float* q = (const float*)d_in[0];
    const float* k = (const float*)d_in[1];
    float* v = (float*)d_in[2];
    const float* beta = (const float*)d_in[3];
    float* out = (float*)d_out;

    const size_t NE = (size_t)BH * LSEQ * DK;
    u16* qb16 = (u16*)d_ws;
    u16* wb16 = qb16 + NE;
    u16* kT16 = wb16 + NE;
    u16* A16  = kT16 + NE;

    prep_kernel<<<dim3(BH*NC), dim3(256), 0, stream>>>(q, k, v, beta, qb16, wb16, kT16, A16);
    scan_kernel<<<dim3(8*BH), dim3(256), 0, stream>>>(qb16, wb16, kT16, A16, v, out);
}